// Round 4
// baseline (8148.584 us; speedup 1.0000x reference)
//
#include <hip/hip_runtime.h>
#include <stdint.h>

// VQ-VAE vector-quantize, fused: distances + argmin + gather + loss.
// x: [65536, 256] fp32, dict: [256, 1024] fp32.
// out: q_ste [65536*256] fp32, then loss scalar at out[65536*256].
//
// NUMERICS (bit-exact vs np reference, verified absmax 0.0 in R2/R3 — DO NOT CHANGE):
//  - row norm ||f||^2: np pairwise tree (two 128-halves, 8 accumulators,
//    unfused squares, fixed combine tree; 0+sq == sq so zero-init is exact)
//  - enorm ||e||^2: sequential d ascending, unfused square then plain add
//  - dist = fl( fl(A + B) - 2*s ), argmin first-index on exact ties
//  - STE out = fl(x + fl(q - x)); loss on pure q, (1+BETA)/(N*D) scale
//
// PERF (R3 -> R4): R3 was stall-bound (VALUBusy 58%, both pipes under model):
// synchronous stage->barrier->compute exposed global-load latency every step.
// R4: flattened 64-step K-loop, ping-pong LDS buffers, dict staged via async
// global_load_lds (width 16), x staged via regs with load at step top / LDS
// store at step bottom. One barrier per step; loads have a full compute step
// (~4K cyc) in flight before the barrier's vmcnt drain.

#define NROWS 65536
#define DDIM  256
#define KC    1024
#define BM    128     // rows per block
#define BC    256     // codes per ct tile
#define DC    16      // d-chunk per pipeline step
#define NDC   (DDIM / DC)    // 16
#define NCT   (KC / BC)      // 4
#define FXW   160     // fX words per d-slice: 32 row-groups * pitch 5
                      // bank(f-read) = (10*ty + i) % 32 -> 2-way (free)

#define GLOAD_LDS16(gp, lp) __builtin_amdgcn_global_load_lds( \
    (const __attribute__((address_space(1))) void*)(gp),      \
    (__attribute__((address_space(3))) void*)(lp), 16, 0, 0)

// Pre-kernel: codebook column norms (np order: rounded square, then plain add,
// sequential d ascending) + transposed codebook + loss zero-init.
__global__ __launch_bounds__(256) void vq_prep(const float* __restrict__ dict,
                                               float* __restrict__ enorm,
                                               float* __restrict__ dictT,
                                               float* __restrict__ loss) {
#pragma clang fp contract(off)
    int k = blockIdx.x * 256 + threadIdx.x;
    if (k == 0) *loss = 0.f;   // runs before vq_main (stream order)
    float s = 0.f;
    for (int d = 0; d < DDIM; ++d) {
        float v = dict[(size_t)d * KC + k];
        float sq = v * v;          // rounded square (np temp array)
        s = s + sq;                // plain add, NOT fma
        dictT[(size_t)k * DDIM + d] = v;
    }
    enorm[k] = s;
}

__global__ __launch_bounds__(256, 2) void vq_main(const float* __restrict__ x,
                                                  const float* __restrict__ dict,
                                                  const float* __restrict__ enorm,
                                                  const float* __restrict__ dictT,
                                                  float* __restrict__ out,
                                                  float* __restrict__ loss) {
    __shared__ float fXb[2][DC * FXW];   // x tile [d][row-group*5+r], 10 KB each
    __shared__ float dTs[2][DC * BC];    // dict tile [d][code], 16 KB each
    __shared__ float rnormS[BM];         // per-row ||f||^2   (total ~53 KB)

    const int tid = threadIdx.x;
    const int tx  = tid & 15;            // 16 code-groups x 16 codes = 256
    const int ty  = tid >> 4;            // 16 row-groups  x  8 rows  = 128
    const int rowbase = blockIdx.x * BM;

    // ---- staging helpers -------------------------------------------------
    float4 vnx[2];                       // in-flight x chunk (2 float4/thread)
    auto load_fx = [&](int dc) {         // global -> regs (coalesced float4)
        #pragma unroll
        for (int i = 0; i < 2; ++i) {
            int flat4 = i * 256 + tid;   // 0..511
            int row   = flat4 >> 2;      // 0..127
            int c4    = flat4 & 3;       // d-quad 0..3
            vnx[i] = *(const float4*)&x[(size_t)(rowbase + row) * DDIM + dc * DC + c4 * 4];
        }
    };
    auto store_fx = [&](int p) {         // regs -> LDS (transposed, pitch-5 groups)
        float* b = &fXb[p][0];
        #pragma unroll
        for (int i = 0; i < 2; ++i) {
            int flat4 = i * 256 + tid;
            int row   = flat4 >> 2;
            int c4    = flat4 & 3;
            int g = row >> 2, rr = row & 3;
            b[(c4 * 4 + 0) * FXW + g * 5 + rr] = vnx[i].x;
            b[(c4 * 4 + 1) * FXW + g * 5 + rr] = vnx[i].y;
            b[(c4 * 4 + 2) * FXW + g * 5 + rr] = vnx[i].z;
            b[(c4 * 4 + 3) * FXW + g * 5 + rr] = vnx[i].w;
        }
    };
    auto stage_dict = [&](int ct, int dc, int p) {   // async DMA global -> LDS
        #pragma unroll
        for (int i = 0; i < 4; ++i) {
            int flat4 = i * 256 + tid;   // 0..1023
            int dd = flat4 >> 6;         // uniform per wave
            int c4 = (flat4 & 63) * 4;   // lane*4 -> LDS dest = base + lane*16 ✓
            GLOAD_LDS16(&dict[(size_t)(dc * DC + dd) * KC + ct * BC + c4],
                        &dTs[p][dd * BC + c4]);
        }
    };

    // ---- Phase N: row norms, np pairwise (bit-exact), pipelined ----------
    {
        float r8[8] = {0.f, 0.f, 0.f, 0.f, 0.f, 0.f, 0.f, 0.f};
        float halfv0 = 0.f;
        load_fx(0); store_fx(0);
        stage_dict(0, 0, 0);             // prefetch first dict tile early
        __syncthreads();
        for (int c = 0; c < NDC; ++c) {
            const int p = c & 1;
            if (c < NDC - 1) load_fx(c + 1);
            if (tid < BM) {
#pragma clang fp contract(off)
                #pragma unroll
                for (int dd = 0; dd < DC; ++dd) {   // element e = c*16+dd, e&7 == dd&7
                    float v  = fXb[p][dd * FXW + (tid >> 2) * 5 + (tid & 3)];
                    float sq = v * v;
                    r8[dd & 7] = r8[dd & 7] + sq;
                }
            }
            if (c < NDC - 1) store_fx(1 - p);
            if (tid < BM) {
                if (c == 7) {           // half boundary at element 128
#pragma clang fp contract(off)
                    halfv0 = ((r8[0] + r8[1]) + (r8[2] + r8[3]))
                           + ((r8[4] + r8[5]) + (r8[6] + r8[7]));
                    #pragma unroll
                    for (int j = 0; j < 8; ++j) r8[j] = 0.f;
                }
                if (c == NDC - 1) {
#pragma clang fp contract(off)
                    float h1 = ((r8[0] + r8[1]) + (r8[2] + r8[3]))
                             + ((r8[4] + r8[5]) + (r8[6] + r8[7]));
                    rnormS[tid] = halfv0 + h1;
                }
            }
            __syncthreads();
        }
    }

    float Arow[8];
    #pragma unroll
    for (int r = 0; r < 8; ++r) Arow[r] = rnormS[ty * 8 + r];

    float minv[8];
    int   mini[8];
    #pragma unroll
    for (int r = 0; r < 8; ++r) { minv[r] = 3.4e38f; mini[r] = 0; }

    // ---- Main: 64 pipelined steps (ct = s>>4, dc = s&15) -----------------
    // dTs[0] already holds tile (ct0,dc0); restore fX chunk 0 into buf 0.
    load_fx(0); store_fx(0);
    __syncthreads();

    float acc[8][16];
    for (int s = 0; s < NCT * NDC; ++s) {
        const int ct = s >> 4, dc = s & 15, p = s & 1;
        if (s < NCT * NDC - 1) {
            const int ns = s + 1;
            stage_dict(ns >> 4, ns & 15, 1 - p);   // async into 1-p
            load_fx(ns & 15);                      // global -> regs
        }
        if (dc == 0) {
            #pragma unroll
            for (int r = 0; r < 8; ++r)
                #pragma unroll
                for (int j = 0; j < 16; ++j) acc[r][j] = 0.f;
        }
        #pragma unroll
        for (int dd = 0; dd < DC; ++dd) {
            const float4 f0 = *(const float4*)&fXb[p][dd * FXW + (ty * 2) * 5];
            const float4 f1 = *(const float4*)&fXb[p][dd * FXW + (ty * 2 + 1) * 5];
            const float4 e0 = *(const float4*)&dTs[p][dd * BC + tx * 4];
            const float4 e1 = *(const float4*)&dTs[p][dd * BC + 64 + tx * 4];
            const float4 e2 = *(const float4*)&dTs[p][dd * BC + 128 + tx * 4];
            const float4 e3 = *(const float4*)&dTs[p][dd * BC + 192 + tx * 4];
            const float fr[8]  = {f0.x, f0.y, f0.z, f0.w, f1.x, f1.y, f1.z, f1.w};
            const float ec[16] = {e0.x, e0.y, e0.z, e0.w, e1.x, e1.y, e1.z, e1.w,
                                  e2.x, e2.y, e2.z, e2.w, e3.x, e3.y, e3.z, e3.w};
            #pragma unroll
            for (int r = 0; r < 8; ++r)
                #pragma unroll
                for (int j = 0; j < 16; ++j)
                    acc[r][j] = fmaf(fr[r], ec[j], acc[r][j]);
        }
        if (s < NCT * NDC - 1) store_fx(1 - p);    // regs -> LDS[1-p]
        if (dc == NDC - 1) {
            // dist = fl( fl(A + B) - 2*s ) — np rounding chain (fma of
            // t1 - 2*acc is bit-identical: 2*acc exact). Codes ascend with
            // (ct, j) for fixed tx -> strict < keeps FIRST min index.
            const int cbase = ct * BC;
            float en[16];
            #pragma unroll
            for (int j = 0; j < 16; ++j)
                en[j] = enorm[cbase + (j >> 2) * 64 + tx * 4 + (j & 3)];
            #pragma unroll
            for (int r = 0; r < 8; ++r)
                #pragma unroll
                for (int j = 0; j < 16; ++j) {
                    int code = cbase + (j >> 2) * 64 + tx * 4 + (j & 3);
                    float t1 = Arow[r] + en[j];
                    float dist = t1 - 2.0f * acc[r][j];
                    if (dist < minv[r]) { minv[r] = dist; mini[r] = code; }
                }
        }
        __syncthreads();
    }

    // Cross-lane argmin over the 16 tx lanes (xor<16 stays in-wave; lane =
    // (ty&3)*16 + tx). Tie -> smaller index (first occurrence).
    #pragma unroll
    for (int m = 1; m < 16; m <<= 1)
        #pragma unroll
        for (int r = 0; r < 8; ++r) {
            float ov = __shfl_xor(minv[r], m, 64);
            int   oi = __shfl_xor(mini[r], m, 64);
            if (ov < minv[r] || (ov == minv[r] && oi < mini[r])) {
                minv[r] = ov; mini[r] = oi;
            }
        }

    __syncthreads();                 // dTs no longer needed: alias as idx store
    int* idx_s = (int*)&dTs[0][0];
    if (tx == 0) {
        #pragma unroll
        for (int r = 0; r < 8; ++r) idx_s[ty * 8 + r] = mini[r];
    }
    __syncthreads();

    // Epilogue: gather codebook row (dictT L2-resident), re-read x (L3-hot),
    // emulate STE out = fl(x + fl(q-x)), loss on pure q (before STE).
    float lsum = 0.f;
    {
#pragma clang fp contract(off)
        for (int i = 0; i < BM; ++i) {
            int k = idx_s[i];
            float qv = dictT[(size_t)k * DDIM + tid];
            float xv = x[(size_t)(rowbase + i) * DDIM + tid];
            float diff = qv - xv;                                 // fl(q - x)
            out[(size_t)(rowbase + i) * DDIM + tid] = xv + diff;  // fl(x + fl(q-x))
            float d = xv - qv;
            float dsq = d * d;
            lsum = lsum + dsq;
        }
    }
    #pragma unroll
    for (int off = 32; off > 0; off >>= 1)
        lsum += __shfl_down(lsum, off, 64);
    if ((tid & 63) == 0)
        atomicAdd(loss, lsum * (1.25f / 16777216.0f));  // (1+BETA)/(N*D)
}

extern "C" void kernel_launch(void* const* d_in, const int* in_sizes, int n_in,
                              void* d_out, int out_size, void* d_ws, size_t ws_size,
                              hipStream_t stream) {
    (void)in_sizes; (void)n_in; (void)out_size; (void)ws_size;
    const float* x    = (const float*)d_in[0];
    const float* dict = (const float*)d_in[1];
    float* out   = (float*)d_out;
    float* enorm = (float*)d_ws;                 // 1024 floats
    float* dictT = enorm + KC;                   // 1024*256 floats (1 MB)
    float* loss  = out + (size_t)NROWS * DDIM;   // scalar slot after q

    vq_prep<<<KC / 256, 256, 0, stream>>>(dict, enorm, dictT, loss);
    vq_main<<<NROWS / BM, 256, 0, stream>>>(x, dict, enorm, dictT, out, loss);
}

// Round 5
// 531.674 us; speedup vs baseline: 15.3263x; 15.3263x over previous
//
#include <hip/hip_runtime.h>

// VQ-VAE vector-quantize, fused: distances + argmin + gather + loss.
// x: [65536, 256] fp32, dict: [256, 1024] fp32.
// out: q_ste [65536*256] fp32, then loss scalar at out[65536*256].
//
// NUMERICS (bit-exact vs np reference, verified absmax 0.0 R2/R3/R4 — DO NOT CHANGE):
//  - row norm ||f||^2: np pairwise tree (two 128-halves, 8 accumulators,
//    unfused squares, fixed combine tree; 0+sq == sq so zero-init is exact)
//  - enorm ||e||^2: sequential d ascending, unfused square then plain add
//  - dist = fl( fl(A + B) - 2*s ), argmin first-index on exact ties
//  - STE out = fl(x + fl(q - x)); loss on pure q, (1+BETA)/(N*D) scale
//
// PERF (R4 -> R5): R4's flat pipelined loop spilled to scratch (WRITE_SIZE
// 16.5 GB = allocator gave up on acc+prefetch regs+lambdas+dynamic parity).
// R5 keeps the one-barrier-per-step pipeline but: dict prefetch via async
// global_load_lds (zero VGPR), x prefetch regs dead before compute, unroll-2
// step loop for compile-time buffer parity, no lambdas.

#define NROWS 65536
#define DDIM  256
#define KC    1024
#define BM    128            // rows per block
#define BC    256            // codes per ct tile
#define DC    16             // d-chunk per pipeline step
#define NDC   16             // DDIM/DC
#define NCT   4              // KC/BC
#define NSTEP 64             // NCT*NDC
#define FXW   160            // 32 row-groups * pitch 5 (160%32==0 -> clean banks)

#define GLOAD_LDS16(gp, lp) __builtin_amdgcn_global_load_lds( \
    (const __attribute__((address_space(1))) void*)(gp),      \
    (__attribute__((address_space(3))) void*)(lp), 16, 0, 0)

// x chunk [128 rows][16 d] -> LDS transposed [d][row-group*5+r]. 2 float4/thread,
// regs die immediately (stores right after the vmcnt wait).
#define STAGE_FX(dstbuf, dc_) do {                                              \
    const int r0_ = tid >> 2, c0_ = tid & 3;                                    \
    const float4 v0_ = *(const float4*)&x[(size_t)(rowbase + r0_) * DDIM + (dc_) * DC + c0_ * 4];      \
    const float4 v1_ = *(const float4*)&x[(size_t)(rowbase + 64 + r0_) * DDIM + (dc_) * DC + c0_ * 4]; \
    float* b0_ = (dstbuf) + (c0_ * 4) * FXW + (r0_ >> 2) * 5 + (r0_ & 3);       \
    b0_[0 * FXW] = v0_.x; b0_[1 * FXW] = v0_.y;                                 \
    b0_[2 * FXW] = v0_.z; b0_[3 * FXW] = v0_.w;                                 \
    float* b1_ = b0_ + 16 * 5; /* +64 rows = +16 groups */                      \
    b1_[0 * FXW] = v1_.x; b1_[1 * FXW] = v1_.y;                                 \
    b1_[2 * FXW] = v1_.z; b1_[3 * FXW] = v1_.w;                                 \
} while (0)

// dict tile [16 d][256 codes] via async DMA: lds dest = uniform + lane*16.
#define STAGE_DICT(pbuf, ct_, dc_) do {                                         \
    _Pragma("unroll")                                                           \
    for (int i_ = 0; i_ < 4; ++i_) {                                            \
        int flat_ = i_ * 256 + tid;                                             \
        int dd_ = flat_ >> 6;            /* wave-uniform */                     \
        int l4_ = (flat_ & 63) * 4;      /* lane*4 floats = lane*16 B */        \
        GLOAD_LDS16(&dict[(size_t)((dc_) * DC + dd_) * KC + (ct_) * BC + l4_],  \
                    (pbuf) + dd_ * BC + l4_);                                   \
    }                                                                           \
} while (0)

// Pre-kernel: codebook column norms (np order: rounded square then plain add,
// sequential d ascending) + transposed codebook + loss zero-init.
__global__ __launch_bounds__(256) void vq_prep(const float* __restrict__ dict,
                                               float* __restrict__ enorm,
                                               float* __restrict__ dictT,
                                               float* __restrict__ loss) {
#pragma clang fp contract(off)
    int k = blockIdx.x * 256 + threadIdx.x;
    if (k == 0) *loss = 0.f;   // runs before vq_main (stream order)
    float s = 0.f;
    #pragma unroll 8
    for (int d = 0; d < DDIM; ++d) {
        float v = dict[(size_t)d * KC + k];
        float sq = v * v;          // rounded square (np temp array)
        s = s + sq;                // plain add, NOT fma (chain stays sequential)
        dictT[(size_t)k * DDIM + d] = v;
    }
    enorm[k] = s;
}

__global__ __launch_bounds__(256, 2) void vq_main(const float* __restrict__ x,
                                                  const float* __restrict__ dict,
                                                  const float* __restrict__ enorm,
                                                  const float* __restrict__ dictT,
                                                  float* __restrict__ out,
                                                  float* __restrict__ loss) {
    __shared__ float fXb[2][DC * FXW];   // 10 KB each
    __shared__ float dTs[2][DC * BC];    // 16 KB each
    __shared__ float rnormS[BM];         // total ~53 KB -> 2 blocks/CU

    const int tid = threadIdx.x;
    const int tx  = tid & 15;            // 16 code-groups x 16 codes = 256
    const int ty  = tid >> 4;            // 16 row-groups  x  8 rows  = 128
    const int rowbase = blockIdx.x * BM;

    // ---- Phase N: row norms, np pairwise (bit-exact). Single-buffer sync;
    // also kick off the first dict tile DMA (lands during this phase).
    STAGE_DICT(&dTs[0][0], 0, 0);
    {
        float r8[8] = {0.f, 0.f, 0.f, 0.f, 0.f, 0.f, 0.f, 0.f};
        float halfv0 = 0.f;
        for (int c = 0; c < NDC; ++c) {
            STAGE_FX(&fXb[0][0], c);
            __syncthreads();
            if (tid < BM) {
#pragma clang fp contract(off)
                #pragma unroll
                for (int dd = 0; dd < DC; ++dd) {   // elem e=c*16+dd; e%8 == dd%8
                    float v  = fXb[0][dd * FXW + (tid >> 2) * 5 + (tid & 3)];
                    float sq = v * v;
                    r8[dd & 7] = r8[dd & 7] + sq;
                }
                if (c == 7) {                       // half boundary at elem 128
#pragma clang fp contract(off)
                    halfv0 = ((r8[0] + r8[1]) + (r8[2] + r8[3]))
                           + ((r8[4] + r8[5]) + (r8[6] + r8[7]));
                    #pragma unroll
                    for (int j = 0; j < 8; ++j) r8[j] = 0.f;
                }
                if (c == NDC - 1) {
#pragma clang fp contract(off)
                    float h1 = ((r8[0] + r8[1]) + (r8[2] + r8[3]))
                             + ((r8[4] + r8[5]) + (r8[6] + r8[7]));
                    rnormS[tid] = halfv0 + h1;
                }
            }
            __syncthreads();
        }
    }

    float Arow[8];
    #pragma unroll
    for (int r = 0; r < 8; ++r) Arow[r] = rnormS[ty * 8 + r];

    float minv[8];
    int   mini[8];
    #pragma unroll
    for (int r = 0; r < 8; ++r) { minv[r] = 3.4e38f; mini[r] = 0; }

    // ---- Main: 64 steps, one barrier each. dTs[0] holds tile (0,0) already.
    STAGE_FX(&fXb[0][0], 0);
    __syncthreads();

    float acc[8][16];
    #pragma unroll 2                     // compile-time buffer parity
    for (int s = 0; s < NSTEP; ++s) {
        const int p = s & 1;
        if (s < NSTEP - 1) {
            const int ns = s + 1;
            STAGE_DICT(&dTs[1 - p][0], ns >> 4, ns & 15);  // async, 0 regs
            STAGE_FX(&fXb[1 - p][0], ns & 15);             // regs die here
        }
        if ((s & 15) == 0) {
            #pragma unroll
            for (int r = 0; r < 8; ++r)
                #pragma unroll
                for (int j = 0; j < 16; ++j) acc[r][j] = 0.f;
        }
        #pragma unroll 4
        for (int dd = 0; dd < DC; ++dd) {
            const float4 f0 = *(const float4*)&fXb[p][dd * FXW + (ty * 2) * 5];
            const float4 f1 = *(const float4*)&fXb[p][dd * FXW + (ty * 2 + 1) * 5];
            const float4 e0 = *(const float4*)&dTs[p][dd * BC + tx * 4];
            const float4 e1 = *(const float4*)&dTs[p][dd * BC + 64 + tx * 4];
            const float4 e2 = *(const float4*)&dTs[p][dd * BC + 128 + tx * 4];
            const float4 e3 = *(const float4*)&dTs[p][dd * BC + 192 + tx * 4];
            const float fr[8]  = {f0.x, f0.y, f0.z, f0.w, f1.x, f1.y, f1.z, f1.w};
            const float ec[16] = {e0.x, e0.y, e0.z, e0.w, e1.x, e1.y, e1.z, e1.w,
                                  e2.x, e2.y, e2.z, e2.w, e3.x, e3.y, e3.z, e3.w};
            #pragma unroll
            for (int r = 0; r < 8; ++r)
                #pragma unroll
                for (int j = 0; j < 16; ++j)
                    acc[r][j] = fmaf(fr[r], ec[j], acc[r][j]);
        }
        if ((s & 15) == 15) {
            // dist = fl( fl(A + B) - 2*s ) — np rounding chain (fma of
            // t1 - 2*acc bit-identical: 2*acc exact). Codes ascend with
            // (ct, j) for fixed tx -> strict < keeps FIRST min index.
            const int cbase = (s >> 4) * BC;
            float en[16];
            #pragma unroll
            for (int j = 0; j < 16; ++j)
                en[j] = enorm[cbase + (j >> 2) * 64 + tx * 4 + (j & 3)];
            #pragma unroll
            for (int r = 0; r < 8; ++r)
                #pragma unroll
                for (int j = 0; j < 16; ++j) {
                    int code = cbase + (j >> 2) * 64 + tx * 4 + (j & 3);
                    float t1 = Arow[r] + en[j];
                    float dist = t1 - 2.0f * acc[r][j];
                    if (dist < minv[r]) { minv[r] = dist; mini[r] = code; }
                }
        }
        __syncthreads();
    }

    // Cross-lane argmin over the 16 tx lanes (xor<16 stays in-wave; lane =
    // (ty&3)*16 + tx). Tie -> smaller index (first occurrence).
    #pragma unroll
    for (int m = 1; m < 16; m <<= 1)
        #pragma unroll
        for (int r = 0; r < 8; ++r) {
            float ov = __shfl_xor(minv[r], m, 64);
            int   oi = __shfl_xor(mini[r], m, 64);
            if (ov < minv[r] || (ov == minv[r] && oi < mini[r])) {
                minv[r] = ov; mini[r] = oi;
            }
        }

    int* idx_s = (int*)&dTs[0][0];       // loop-end barrier covers last compute
    if (tx == 0) {
        #pragma unroll
        for (int r = 0; r < 8; ++r) idx_s[ty * 8 + r] = mini[r];
    }
    __syncthreads();

    // Epilogue: gather codebook row (dictT L2-resident), re-read x (L3-hot),
    // emulate STE out = fl(x + fl(q-x)), loss on pure q (before STE).
    float lsum = 0.f;
    {
#pragma clang fp contract(off)
        for (int i = 0; i < BM; ++i) {
            int k = idx_s[i];
            float qv = dictT[(size_t)k * DDIM + tid];
            float xv = x[(size_t)(rowbase + i) * DDIM + tid];
            float diff = qv - xv;                                 // fl(q - x)
            out[(size_t)(rowbase + i) * DDIM + tid] = xv + diff;  // fl(x + fl(q-x))
            float d = xv - qv;
            float dsq = d * d;
            lsum = lsum + dsq;
        }
    }
    #pragma unroll
    for (int off = 32; off > 0; off >>= 1)
        lsum += __shfl_down(lsum, off, 64);
    if ((tid & 63) == 0)
        atomicAdd(loss, lsum * (1.25f / 16777216.0f));  // (1+BETA)/(N*D)
}

extern "C" void kernel_launch(void* const* d_in, const int* in_sizes, int n_in,
                              void* d_out, int out_size, void* d_ws, size_t ws_size,
                              hipStream_t stream) {
    (void)in_sizes; (void)n_in; (void)out_size; (void)ws_size;
    const float* x    = (const float*)d_in[0];
    const float* dict = (const float*)d_in[1];
    float* out   = (float*)d_out;
    float* enorm = (float*)d_ws;                 // 1024 floats
    float* dictT = enorm + KC;                   // 1024*256 floats (1 MB)
    float* loss  = out + (size_t)NROWS * DDIM;   // scalar slot after q

    vq_prep<<<KC / 256, 256, 0, stream>>>(dict, enorm, dictT, loss);
    vq_main<<<NROWS / BM, 256, 0, stream>>>(x, dict, enorm, dictT, out, loss);
}